// Round 15
// baseline (366.682 us; speedup 1.0000x reference)
//
#include <hip/hip_runtime.h>
#include <math.h>

#define T_STEPS 48
#define N_NODES 1000
#define E_EDGES 32000
#define DIN     32
#define H_DIM   64

// ---- workspace layout (4-byte units) ----
#define O_INDEG  0         // int[1000]
#define O_FILL   1024      // int[1000]
#define O_ROWPTR 2048      // int[1001]
#define O_CSRC   4096      // int[32000]
#define O_CNORM  36864     // f32[32000]
#define O_DINV   69632     // f32[1000]
#define O_SELF   70656     // f32[1000]
#define O_BUF0   71680                    // f32[48*64000]  T1 -> T2 -> part
#define O_BUF1   (71680 + 3072000)        // f32[48*64000]  G1 -> G2
#define O_HSB    (71680 + 6144000)        // bf16[48*64000] HS (main path)
#define WS_NEED_HSB ((size_t)(O_HSB + 1536000) * 4)

typedef __attribute__((ext_vector_type(8))) short short8;       // 8 bf16
typedef __attribute__((ext_vector_type(4))) float f32x4;
typedef __attribute__((ext_vector_type(4))) unsigned int uint32x4;

__device__ __forceinline__ float sigmf(float v) { return 1.0f / (1.0f + __expf(-v)); }

// ---------------- setup ----------------
__global__ void k_zero(int* __restrict__ p) { p[blockIdx.x * 256 + threadIdx.x] = 0; }

__global__ void k_count(const int* __restrict__ ei, int* __restrict__ indeg) {
  int e = blockIdx.x * 256 + threadIdx.x;
  if (e < E_EDGES) atomicAdd(&indeg[ei[E_EDGES + e]], 1);
}

__global__ void k_scan(const int* __restrict__ indeg, int* __restrict__ rowptr,
                       float* __restrict__ dinv, float* __restrict__ selfn) {
  __shared__ int sdat[1024];
  int tid = threadIdx.x;
  int v = (tid < N_NODES) ? indeg[tid] : 0;
  sdat[tid] = v;
  __syncthreads();
  for (int off = 1; off < 1024; off <<= 1) {
    int add = (tid >= off) ? sdat[tid - off] : 0;
    __syncthreads();
    sdat[tid] += add;
    __syncthreads();
  }
  if (tid < N_NODES) {
    rowptr[tid + 1] = sdat[tid];
    float di = rsqrtf((float)(v + 1));
    dinv[tid] = di;
    selfn[tid] = di * di;
  }
  if (tid == 0) rowptr[0] = 0;
}

__global__ void k_scatter(const int* __restrict__ ei, const int* __restrict__ rowptr,
                          int* __restrict__ fill, const float* __restrict__ dinv,
                          int* __restrict__ csrc, float* __restrict__ cnorm) {
  int e = blockIdx.x * 256 + threadIdx.x;
  if (e >= E_EDGES) return;
  int s = ei[e], d = ei[E_EDGES + e];
  int pos = atomicAdd(&fill[d], 1);
  int idx = rowptr[d] + pos;
  csrc[idx] = s;
  cnorm[idx] = dinv[s] * dinv[d];
}

// ---------------- T1 = x @ Wg1 ----------------
__global__ void __launch_bounds__(256) k_t1(const float* __restrict__ x,
                                            const float* __restrict__ Wg1,
                                            float* __restrict__ T1) {
  __shared__ float sWT[H_DIM * 36];     // transposed: sWT[h][k]
  __shared__ float sx[4][DIN];
  const int tid = threadIdx.x, wv = tid >> 6, h = tid & 63;
  for (int i = tid; i < DIN * H_DIM; i += 256) sWT[(i & 63) * 36 + (i >> 6)] = Wg1[i];
  __syncthreads();
  const int r0 = blockIdx.x * 64 + wv * 16;
  const float4* wrow = (const float4*)&sWT[h * 36];
  for (int it = 0; it < 16; ++it) {
    const int r = r0 + it;
    if (h < DIN) sx[wv][h] = x[r * DIN + h];   // wave-local
    float acc = 0.f;
    const float4* xp = (const float4*)&sx[wv][0];
#pragma unroll
    for (int k4 = 0; k4 < 8; ++k4) {
      float4 xv = xp[k4], wv4 = wrow[k4];
      acc += xv.x * wv4.x + xv.y * wv4.y + xv.z * wv4.z + xv.w * wv4.w;
    }
    T1[r * H_DIM + h] = acc;
  }
}

// ---------------- gather: 4-edge-wide, float4 per lane ----------------
// lane = eq(2b) x h4(4b): one wave instruction loads 4 edges x 256B.
// 2-deep rotation; eq-group partials folded by shfl_xor(16),(32).
#define ECHUNK 768
__global__ void __launch_bounds__(256) k_gath(const float* __restrict__ Tall,
                                              const float* __restrict__ bias,
                                              const int* __restrict__ rowptr,
                                              const int* __restrict__ csrc,
                                              const float* __restrict__ cnorm,
                                              const float* __restrict__ selfn,
                                              float* __restrict__ Dall, int relu) {
  __shared__ int   s_src[ECHUNK];
  __shared__ float s_wt[ECHUNK];
  const int tid = threadIdx.x, wv = tid >> 6, lane = tid & 63;
  const int h4 = lane & 15, eq = lane >> 4;
  const int t = blockIdx.x >> 6, nb16 = (blockIdx.x & 63) * 16;
  if (nb16 >= N_NODES) return;
  const float* Tsrc = Tall + t * 64000;
  float* dst = Dall + t * 64000;
  const int nE = (nb16 + 16 < N_NODES) ? nb16 + 16 : N_NODES;
  const int r0 = rowptr[nb16], r1 = rowptr[nE];
  const int tot = r1 - r0;
  const bool fits = (tot <= ECHUNK);
  if (fits)
    for (int i = tid; i < tot; i += 256) { s_src[i] = csrc[r0 + i]; s_wt[i] = cnorm[r0 + i]; }
  __syncthreads();
  for (int i = 0; i < 4; ++i) {
    const int n = nb16 + wv * 4 + i;
    if (n >= N_NODES) continue;
    const int a = rowptr[n] - r0;            // LDS-relative start
    const int cnt = rowptr[n] - r0 >= 0 ? rowptr[n + 1] - rowptr[n] : 0;
    float4 acc = make_float4(0.f, 0.f, 0.f, 0.f);
    if (eq == 0) {
      const float4 sv = *(const float4*)&Tsrc[n * 64 + h4 * 4];
      const float sw = selfn[n];
      acc.x = sw * sv.x; acc.y = sw * sv.y; acc.z = sw * sv.z; acc.w = sw * sv.w;
    }
    if (fits) {
      int e = a + eq;
      const int end = a + cnt;
      float4 pv = make_float4(0.f, 0.f, 0.f, 0.f);
      float pw = 0.f;
      bool have = (e < end);
      if (have) {
        const int s = s_src[e]; pw = s_wt[e];
        pv = *(const float4*)&Tsrc[s * 64 + h4 * 4];
      }
      e += 4;
      while (__any(have)) {
        float4 nv = make_float4(0.f, 0.f, 0.f, 0.f);
        float nw = 0.f;
        const bool hnx = (e < end);
        if (hnx) {
          const int s2 = s_src[e]; nw = s_wt[e];
          nv = *(const float4*)&Tsrc[s2 * 64 + h4 * 4];
        }
        acc.x += pw * pv.x; acc.y += pw * pv.y; acc.z += pw * pv.z; acc.w += pw * pv.w;
        pv = nv; pw = nw; have = hnx; e += 4;
      }
    } else {
      // safety fallback (never taken for this graph): scalar global loop
      const int A = rowptr[n], B = rowptr[n + 1];
      for (int e2 = A + eq; e2 < B; e2 += 4) {
        const int s = csrc[e2];
        const float w = cnorm[e2];
        const float4 v = *(const float4*)&Tsrc[s * 64 + h4 * 4];
        acc.x += w * v.x; acc.y += w * v.y; acc.z += w * v.z; acc.w += w * v.w;
      }
    }
    // fold eq groups (lanes differ in bits 4,5)
    acc.x += __shfl_xor(acc.x, 16, 64); acc.y += __shfl_xor(acc.y, 16, 64);
    acc.z += __shfl_xor(acc.z, 16, 64); acc.w += __shfl_xor(acc.w, 16, 64);
    acc.x += __shfl_xor(acc.x, 32, 64); acc.y += __shfl_xor(acc.y, 32, 64);
    acc.z += __shfl_xor(acc.z, 32, 64); acc.w += __shfl_xor(acc.w, 32, 64);
    if (eq == 0) {
      const float4 b4 = *(const float4*)&bias[h4 * 4];
      float4 o = make_float4(acc.x + b4.x, acc.y + b4.y, acc.z + b4.z, acc.w + b4.w);
      if (relu) {
        o.x = fmaxf(o.x, 0.f); o.y = fmaxf(o.y, 0.f);
        o.z = fmaxf(o.z, 0.f); o.w = fmaxf(o.w, 0.f);
      }
      *(float4*)&dst[n * 64 + h4 * 4] = o;
    }
  }
}

// ---------------- T2 = G1 @ Wg2 (48000 x 64 x 64) ----------------
__global__ void __launch_bounds__(256) k_mm2(const float* __restrict__ G1,
                                             const float* __restrict__ Wg2,
                                             float* __restrict__ T2) {
  __shared__ float sW[H_DIM * H_DIM];   // [k][h] broadcast form, conflict-free
  __shared__ float sx[4][H_DIM];
  const int tid = threadIdx.x, wv = tid >> 6, h = tid & 63;
  for (int i = tid; i < H_DIM * H_DIM; i += 256) sW[i] = Wg2[i];
  __syncthreads();
  const int r0 = blockIdx.x * 64 + wv * 16;
  for (int it = 0; it < 16; ++it) {
    const int r = r0 + it;
    sx[wv][h] = G1[r * 64 + h];   // wave-local write then read
    float acc = 0.f;
#pragma unroll
    for (int k = 0; k < H_DIM; ++k) acc += sx[wv][k] * sW[k * H_DIM + h];
    T2[r * 64 + h] = acc;
  }
}

// ---------------- LSTM scan: 1 node / block; writes bf16 HS directly ----------------
__global__ void __launch_bounds__(256) k_lstm(const float* __restrict__ G2,
                                              const float* __restrict__ h0,
                                              const float* __restrict__ c0,
                                              const float* __restrict__ Wih,
                                              const float* __restrict__ Whh,
                                              const float* __restrict__ bih,
                                              const float* __restrict__ bhh,
                                              float* __restrict__ hsg,
                                              unsigned short* __restrict__ hsb,
                                              float* __restrict__ outp) {
  const int tid = threadIdx.x, nb = blockIdx.x;
  __shared__ float sh[64];
  __shared__ float sg2[2][64];
  __shared__ float sgates[256];
  float4 Wih4[16], Whh4[16];
  {
    const float4* wp = (const float4*)(Wih + tid * H_DIM);
    const float4* vp = (const float4*)(Whh + tid * H_DIM);
#pragma unroll
    for (int k = 0; k < 16; ++k) { Wih4[k] = wp[k]; Whh4[k] = vp[k]; }
  }
  const float bsum = bih[tid] + bhh[tid];
  float creg = 0.f;
  if (tid < 64) {
    sh[tid] = h0[nb * 64 + tid];
    creg = c0[nb * 64 + tid];
    sg2[0][tid] = G2[nb * 64 + tid];
  }
  __syncthreads();
  for (int t = 0; t < T_STEPS; ++t) {
    const int cur = t & 1;
    float gnext = 0.f;
    if (t < T_STEPS - 1 && tid < 64) gnext = G2[(t + 1) * 64000 + nb * 64 + tid];
    float gv = bsum;
    const float4* gp = (const float4*)&sg2[cur][0];
    const float4* hp = (const float4*)sh;
#pragma unroll
    for (int k = 0; k < 16; ++k) {
      float4 a = gp[k], b = hp[k];
      gv += a.x * Wih4[k].x + a.y * Wih4[k].y + a.z * Wih4[k].z + a.w * Wih4[k].w;
      gv += b.x * Whh4[k].x + b.y * Whh4[k].y + b.z * Whh4[k].z + b.w * Whh4[k].w;
    }
    sgates[tid] = gv;
    __syncthreads();
    if (tid < 64) {
      float iv = sgates[tid], fv = sgates[64 + tid], gg = sgates[128 + tid], ov = sgates[192 + tid];
      float cn = sigmf(fv) * creg + sigmf(iv) * tanhf(gg);
      float hn = sigmf(ov) * tanhf(cn);
      creg = cn;
      sh[tid] = hn;
      if (hsb) {
        unsigned u = __float_as_uint(hn);
        u += 0x7fff + ((u >> 16) & 1);                 // RNE
        hsb[t * 64000 + nb * 64 + tid] = (unsigned short)(u >> 16);
      } else {
        hsg[t * 64000 + nb * 64 + tid] = hn;
      }
      if (t < T_STEPS - 1) sg2[cur ^ 1][tid] = gnext;
    }
    __syncthreads();
  }
  if (tid < 64) {
    outp[48000 + nb * 64 + tid] = sh[tid];
    outp[48000 + 64000 + nb * 64 + tid] = creg;
  }
}

// ---------------- HS f32 -> bf16 (fallback only) ----------------
__global__ void k_cvt(const float* __restrict__ src, unsigned* __restrict__ dst) {
  const int id = blockIdx.x * 256 + threadIdx.x;   // 768000 float4s
  const float4 v = ((const float4*)src)[id];
  unsigned lo, hi;
  asm("v_cvt_pk_bf16_f32 %0, %1, %2" : "=v"(lo) : "v"(v.x), "v"(v.y));
  asm("v_cvt_pk_bf16_f32 %0, %1, %2" : "=v"(hi) : "v"(v.z), "v"(v.w));
  ((uint2*)dst)[id] = make_uint2(lo, hi);
}

// ---------------- final projection: out = HS @ Wlin^T via bf16 MFMA ----------------
// Pure W-stream, no LDS/barriers. R15: union -> bit_cast (registers only) +
// explicit next-iter A/B register prefetch (uniform guard).
__global__ void __launch_bounds__(256) k_gemmM(const unsigned short* __restrict__ hsb,
                                               const float* __restrict__ Wlin,
                                               float* __restrict__ part) {
  const int tid = threadIdx.x;
  const int kc = blockIdx.x & 15, nt = blockIdx.x >> 4;   // kc->XCD; nt 0..62
  const int wv = tid >> 6, l = tid & 63;
  const int lr = l & 15, kg = l >> 4;
  const int kcbase = kc * 4000;
  const int kp = kc * 4 + wv;

  const unsigned short* ap0 = hsb + (size_t)(0  + lr) * 64000 + kcbase + kg * 8 + wv * 32;
  const unsigned short* ap1 = hsb + (size_t)(16 + lr) * 64000 + kcbase + kg * 8 + wv * 32;
  const unsigned short* ap2 = hsb + (size_t)(32 + lr) * 64000 + kcbase + kg * 8 + wv * 32;
  int nrow = nt * 16 + lr; if (nrow > N_NODES - 1) nrow = N_NODES - 1;
  const float* bp = Wlin + (size_t)nrow * 64000 + kcbase + kg * 8 + wv * 32;

  f32x4 acc0 = {0.f, 0.f, 0.f, 0.f}, acc1 = acc0, acc2 = acc0;

  short8 a0c = *(const short8*)ap0;
  short8 a1c = *(const short8*)ap1;
  short8 a2c = *(const short8*)ap2;
  float4 b0c = *(const float4*)bp;
  float4 b1c = *(const float4*)(bp + 4);

  for (int s = wv; s < 125; s += 4) {
    short8 a0n, a1n, a2n; float4 b0n, b1n;
    if (s + 4 < 125) {                       // wave-uniform guard
      ap0 += 128; ap1 += 128; ap2 += 128; bp += 128;
      a0n = *(const short8*)ap0;
      a1n = *(const short8*)ap1;
      a2n = *(const short8*)ap2;
      b0n = *(const float4*)bp;
      b1n = *(const float4*)(bp + 4);
    }
    unsigned p0, p1, p2, p3;
    asm("v_cvt_pk_bf16_f32 %0, %1, %2" : "=v"(p0) : "v"(b0c.x), "v"(b0c.y));
    asm("v_cvt_pk_bf16_f32 %0, %1, %2" : "=v"(p1) : "v"(b0c.z), "v"(b0c.w));
    asm("v_cvt_pk_bf16_f32 %0, %1, %2" : "=v"(p2) : "v"(b1c.x), "v"(b1c.y));
    asm("v_cvt_pk_bf16_f32 %0, %1, %2" : "=v"(p3) : "v"(b1c.z), "v"(b1c.w));
    uint32x4 bu = {p0, p1, p2, p3};
    const short8 bs = __builtin_bit_cast(short8, bu);
    acc0 = __builtin_amdgcn_mfma_f32_16x16x32_bf16(a0c, bs, acc0, 0, 0, 0);
    acc1 = __builtin_amdgcn_mfma_f32_16x16x32_bf16(a1c, bs, acc1, 0, 0, 0);
    acc2 = __builtin_amdgcn_mfma_f32_16x16x32_bf16(a2c, bs, acc2, 0, 0, 0);
    a0c = a0n; a1c = a1n; a2c = a2n; b0c = b0n; b1c = b1n;
  }

  const int n = nt * 16 + lr;
  if (n < N_NODES) {
    const int trow = kg * 4;
    float* base = part + (size_t)(kp * 48) * 1000 + n;
#pragma unroll
    for (int j = 0; j < 4; ++j) base[(0  + trow + j) * 1000] = acc0[j];
#pragma unroll
    for (int j = 0; j < 4; ++j) base[(16 + trow + j) * 1000] = acc1[j];
#pragma unroll
    for (int j = 0; j < 4; ++j) base[(32 + trow + j) * 1000] = acc2[j];
  }
}

__global__ void k_reduce(const float* __restrict__ part, const float* __restrict__ blin,
                         float* __restrict__ outp) {
  const int id = blockIdx.x * 256 + threadIdx.x;
  if (id >= T_STEPS * N_NODES) return;
  const int t = id / N_NODES, n = id - t * N_NODES;
  float s = blin[n];
#pragma unroll 8
  for (int kp = 0; kp < 64; ++kp) s += part[(size_t)(kp * 48 + t) * 1000 + n];
  outp[id] = s;
}

// ---------------- launch ----------------
extern "C" void kernel_launch(void* const* d_in, const int* in_sizes, int n_in,
                              void* d_out, int out_size, void* d_ws, size_t ws_size,
                              hipStream_t stream) {
  const float* x    = (const float*)d_in[0];
  const int*   ei   = (const int*)d_in[1];
  const float* h0   = (const float*)d_in[2];
  const float* c0   = (const float*)d_in[3];
  const float* Wg1  = (const float*)d_in[4];
  const float* bg1  = (const float*)d_in[5];
  const float* Wg2  = (const float*)d_in[6];
  const float* bg2  = (const float*)d_in[7];
  const float* Wih  = (const float*)d_in[8];
  const float* Whh  = (const float*)d_in[9];
  const float* bih  = (const float*)d_in[10];
  const float* bhh  = (const float*)d_in[11];
  const float* Wlin = (const float*)d_in[12];
  const float* blin = (const float*)d_in[13];
  float* outp = (float*)d_out;
  float* wsf  = (float*)d_ws;
  int*   wsi  = (int*)d_ws;

  int*   indeg  = wsi + O_INDEG;
  int*   fill   = wsi + O_FILL;
  int*   rowptr = wsi + O_ROWPTR;
  int*   csrc   = wsi + O_CSRC;
  float* cnorm  = wsf + O_CNORM;
  float* dinv   = wsf + O_DINV;
  float* selfn  = wsf + O_SELF;
  float* buf0   = wsf + O_BUF0;   // T1 -> T2 -> part
  float* buf1   = wsf + O_BUF1;   // G1 -> G2

  const bool big = ws_size >= WS_NEED_HSB;

  k_zero<<<8, 256, 0, stream>>>(wsi);
  k_count<<<(E_EDGES + 255) / 256, 256, 0, stream>>>(ei, indeg);
  k_scan<<<1, 1024, 0, stream>>>(indeg, rowptr, dinv, selfn);
  k_scatter<<<(E_EDGES + 255) / 256, 256, 0, stream>>>(ei, rowptr, fill, dinv, csrc, cnorm);

  k_t1<<<750, 256, 0, stream>>>(x, Wg1, buf0);
  k_gath<<<3072, 256, 0, stream>>>(buf0, bg1, rowptr, csrc, cnorm, selfn, buf1, 1);  // G1
  k_mm2<<<750, 256, 0, stream>>>(buf1, Wg2, buf0);                                   // T2
  k_gath<<<3072, 256, 0, stream>>>(buf0, bg2, rowptr, csrc, cnorm, selfn, buf1, 0);  // G2

  unsigned short* hsb;
  if (big) {
    hsb = (unsigned short*)(wsf + O_HSB);
    k_lstm<<<1000, 256, 0, stream>>>(buf1, h0, c0, Wih, Whh, bih, bhh,
                                     buf0, hsb, outp);           // bf16 HS direct
  } else {
    k_lstm<<<1000, 256, 0, stream>>>(buf1, h0, c0, Wih, Whh, bih, bhh,
                                     buf0, (unsigned short*)nullptr, outp);  // f32 HS
    k_cvt<<<3000, 256, 0, stream>>>(buf0, (unsigned*)buf1);
    hsb = (unsigned short*)buf1;
  }
  k_gemmM<<<16 * 63, 256, 0, stream>>>(hsb, Wlin, buf0);
  k_reduce<<<(T_STEPS * N_NODES + 255) / 256, 256, 0, stream>>>(buf0, blin, outp);
}